// Round 2
// baseline (294.241 us; speedup 1.0000x reference)
//
#include <hip/hip_runtime.h>
#include <hip/hip_fp16.h>
#include <float.h>

#define C_DEPTH 128
#define H_DIM 128
#define W_DIM 128
#define NPIX (H_DIM * W_DIM)
#define N_SAMP 32
#define N_FINAL 8
#define N_LINES 50000
#define C_HALF 64          // channels per pass: 2 MiB fp16 working set = 1/2 XCD L2
#define LPB 2              // lines per block, one wave per line

typedef float v4f __attribute__((ext_vector_type(4)));

// ---------------------------------------------------------------------------
// Pre-pass: transpose features (C,H,W) fp32 -> (H*W, C) fp16.
// Pad 130 (even) so the read-back can be float2; stores are half2 (4 B/lane,
// full-width 256 B wave stores instead of 128 B).
// ---------------------------------------------------------------------------
__global__ __launch_bounds__(256) void transpose_chw_hwc(
    const float* __restrict__ in, __half* __restrict__ out) {
    __shared__ float tile[64 * 130];
    const int p0 = blockIdx.x * 64;
    const int t = threadIdx.x;

    const int p_local = t & 63;
    const int cg = t >> 6;  // 0..3, each covers 32 channels
    #pragma unroll
    for (int i = 0; i < 32; ++i) {
        const int ch = cg * 32 + i;
        tile[p_local * 130 + ch] = in[ch * NPIX + p0 + p_local];
    }
    __syncthreads();

    const int cp = (t & 63) * 2;  // channel pair 0,2,...,126
    const int pg = t >> 6;        // 0..3, each covers 16 pixels
    #pragma unroll
    for (int i = 0; i < 16; ++i) {
        const int p = pg * 16 + i;
        const float2 f2 = *reinterpret_cast<const float2*>(&tile[p * 130 + cp]);
        *reinterpret_cast<__half2*>(&out[(size_t)(p0 + p) * C_DEPTH + cp]) =
            __floats2half2_rn(f2.x, f2.y);
    }
}

// ---------------------------------------------------------------------------
// Main kernel, channel-split: one launch per 64-channel half so the gather
// working set (2 MiB) is L2-resident per XCD (4 MiB fp16 was exactly at
// capacity -> spill to Infinity Cache).
//
// 1 wave = 1 line. lane = 8 pool-groups (f) x 8 channel-octets (tg).
// Coords/weights computed per-thread in registers (no barrier, no LDS
// round-trip) so all 16 gather loads issue immediately -> deep MLP.
// lines[line] is wave-uniform -> compiler scalarizes to s_load.
// ---------------------------------------------------------------------------
__global__ __launch_bounds__(128) void line_pool_half(
    const __half* __restrict__ ft,      // (H*W, C) fp16 transposed features
    const float* __restrict__ lines,    // (N_LINES, 4)
    float* __restrict__ out,            // (N_LINES, C*N_FINAL) fp32
    const int c_base) {
    __shared__ float o_tile[LPB][C_HALF * 9];

    const int wid  = threadIdx.x >> 6;
    const int lane = threadIdx.x & 63;
    const int line = blockIdx.x * LPB + wid;

    const int f  = lane >> 3;           // pool group: samples 4f..4f+3
    const int tg = lane & 7;            // channel octet within this half
    const int c0 = c_base + tg * 8;     // 8 fp16 = 16 B per corner load

    const float4 l = reinterpret_cast<const float4*>(lines)[line];

    int4   o[4];
    float4 w[4];
    #pragma unroll
    for (int si = 0; si < 4; ++si) {
        const int s = f * 4 + si;
        const float ts = (float)s / 31.0f;  // exact 1.0 at s=31
        const float px = l.x * ts + l.z * (1.0f - ts) - 0.5f;
        const float py = l.y * ts + l.w * (1.0f - ts) - 0.5f;
        // Reference: clamp AFTER floor, weights from the CLAMPED float coords.
        const float px0 = fminf(fmaxf(floorf(px), 0.0f), (float)(W_DIM - 1));
        const float py0 = fminf(fmaxf(floorf(py), 0.0f), (float)(H_DIM - 1));
        const float px1 = fminf(px0 + 1.0f, (float)(W_DIM - 1));
        const float py1 = fminf(py0 + 1.0f, (float)(H_DIM - 1));
        const int ix0 = (int)px0, iy0 = (int)py0;
        const int ix1 = (int)px1, iy1 = (int)py1;
        const float wx0 = px1 - px, wx1 = px - px0;
        const float wy0 = py1 - py, wy1 = py - py0;
        o[si] = make_int4((iy0 * W_DIM + ix0) * C_DEPTH,
                          (iy1 * W_DIM + ix0) * C_DEPTH,
                          (iy0 * W_DIM + ix1) * C_DEPTH,
                          (iy1 * W_DIM + ix1) * C_DEPTH);
        w[si] = make_float4(wy0 * wx0, wy1 * wx0, wy0 * wx1, wy1 * wx1);
    }

    // All 16 gathers issued up front: addresses are pure-register, so the
    // compiler can keep 16 loads in flight per wave.
    float4 r[16];
    #pragma unroll
    for (int si = 0; si < 4; ++si) {
        r[si * 4 + 0] = *reinterpret_cast<const float4*>(ft + o[si].x + c0);
        r[si * 4 + 1] = *reinterpret_cast<const float4*>(ft + o[si].y + c0);
        r[si * 4 + 2] = *reinterpret_cast<const float4*>(ft + o[si].z + c0);
        r[si * 4 + 3] = *reinterpret_cast<const float4*>(ft + o[si].w + c0);
    }

    float acc[8];
    #pragma unroll
    for (int j = 0; j < 8; ++j) acc[j] = -FLT_MAX;

    #pragma unroll
    for (int si = 0; si < 4; ++si) {
        const float4 wv = w[si];
        const __half2* h00 = reinterpret_cast<const __half2*>(&r[si * 4 + 0]);
        const __half2* h10 = reinterpret_cast<const __half2*>(&r[si * 4 + 1]);
        const __half2* h01 = reinterpret_cast<const __half2*>(&r[si * 4 + 2]);
        const __half2* h11 = reinterpret_cast<const __half2*>(&r[si * 4 + 3]);
        #pragma unroll
        for (int k = 0; k < 4; ++k) {
            const float2 f00 = __half22float2(h00[k]);
            const float2 f10 = __half22float2(h10[k]);
            const float2 f01 = __half22float2(h01[k]);
            const float2 f11 = __half22float2(h11[k]);
            const float vx = f00.x * wv.x + f10.x * wv.y + f01.x * wv.z + f11.x * wv.w;
            const float vy = f00.y * wv.x + f10.y * wv.y + f01.y * wv.z + f11.y * wv.w;
            acc[2 * k]     = fmaxf(acc[2 * k],     vx);
            acc[2 * k + 1] = fmaxf(acc[2 * k + 1], vy);
        }
    }

    // (f, c) -> (c, f) through per-wave LDS tile; stride 9 => write side 2-way
    // (free), read-back 2-way (free).
    float* tl = o_tile[wid];
    #pragma unroll
    for (int j = 0; j < 8; ++j) tl[(tg * 8 + j) * 9 + f] = acc[j];
    __syncthreads();

    float* op = out + (size_t)line * (C_DEPTH * N_FINAL)
                    + (size_t)(c_base + lane) * N_FINAL;
    const float* row = &tl[lane * 9];
    const v4f w0 = {row[0], row[1], row[2], row[3]};
    const v4f w1 = {row[4], row[5], row[6], row[7]};
    __builtin_nontemporal_store(w0, reinterpret_cast<v4f*>(op));
    __builtin_nontemporal_store(w1, reinterpret_cast<v4f*>(op) + 1);
}

extern "C" void kernel_launch(void* const* d_in, const int* in_sizes, int n_in,
                              void* d_out, int out_size, void* d_ws, size_t ws_size,
                              hipStream_t stream) {
    const float* feat  = (const float*)d_in[0];   // (128,128,128) fp32
    const float* lines = (const float*)d_in[1];   // (50000,4) fp32
    float* out = (float*)d_out;                   // (50000, 1024) fp32
    __half* ft = (__half*)d_ws;                   // 4 MB transposed fp16 features

    transpose_chw_hwc<<<NPIX / 64, 256, 0, stream>>>(feat, ft);
    // Two sequential channel-half passes: same-stream ordering gives temporal
    // phase separation, so each pass's 2 MiB feature slice stays L2-resident.
    line_pool_half<<<N_LINES / LPB, 128, 0, stream>>>(ft, lines, out, 0);
    line_pool_half<<<N_LINES / LPB, 128, 0, stream>>>(ft, lines, out, C_HALF);
}